// Round 6
// baseline (94.596 us; speedup 1.0000x reference)
//
#include <hip/hip_runtime.h>

typedef unsigned short u16;
typedef u16 u16x8 __attribute__((ext_vector_type(8)));
typedef __bf16 bf16x8 __attribute__((ext_vector_type(8)));
typedef float f32x4 __attribute__((ext_vector_type(4)));

#define MFMA16 __builtin_amdgcn_mfma_f32_16x16x32_bf16

__device__ __forceinline__ u16 f2bf(float f) {
  unsigned u = __builtin_bit_cast(unsigned, f);
  u += 0x7FFFu + ((u >> 16) & 1u);
  return (u16)(u >> 16);
}

// XOR-swizzled LDS byte address for 64-bf16 (128B) rows (guide G4).
__device__ __forceinline__ int swz(int row, int bcol) {
  return row * 128 + (bcol ^ ((row & 7) << 4));
}

__device__ __forceinline__ void gl16(const u16* g, u16* l) {
  __builtin_amdgcn_global_load_lds(
      (const __attribute__((address_space(1))) unsigned int*)g,
      (__attribute__((address_space(3))) unsigned int*)l, 16, 0, 0);
}

// raw workgroup barrier (no vmcnt(0) drain)
__device__ __forceinline__ void BARR() {
  asm volatile("" ::: "memory");
  __builtin_amdgcn_s_barrier();
  asm volatile("" ::: "memory");
}
#define VMCNT(n) asm volatile("s_waitcnt vmcnt(" #n ")" ::: "memory")

// ---------------------------------------------------------------------------
// Flattened fp32 -> bf16 cast. 16M elements total, 8/thread, 8192 blocks.
// ws layout (u16): Wq 0 | Wk 1M | Wv 2M | Wo 3M | Xq 4M | Xk 8M | Xv 12M
// ---------------------------------------------------------------------------
__global__ __launch_bounds__(256)
void cast_all(const float* __restrict__ q, const float* __restrict__ k,
              const float* __restrict__ v, const float* __restrict__ wq,
              const float* __restrict__ wk, const float* __restrict__ wv,
              const float* __restrict__ wo, u16* __restrict__ ws) {
  const long i = ((long)blockIdx.x * 256 + threadIdx.x) * 8;
  const float* s;
  u16* d;
  if (i < 12582912) {  // X region (12M)
    const int seg = (int)(i >> 22);
    const float* xs = (seg == 0) ? q : (seg == 1) ? k : v;
    s = xs + (i & 4194303);
    d = ws + 4194304 + i;
  } else {  // weights (4M)
    const long j = i - 12582912;
    const int seg = (int)(j >> 20);
    const float* wsrc = (seg == 0) ? wq : (seg == 1) ? wk : (seg == 2) ? wv : wo;
    s = wsrc + (j & 1048575);
    d = ws + j;
  }
  float4 v0 = *(const float4*)s;
  float4 v1 = *(const float4*)(s + 4);
  u16x8 p = {f2bf(v0.x), f2bf(v0.y), f2bf(v0.z), f2bf(v0.w),
             f2bf(v1.x), f2bf(v1.y), f2bf(v1.z), f2bf(v1.w)};
  *(u16x8*)d = p;
}

// ---------------------------------------------------------------------------
// QKV projection: 256x256 tile, 8 waves (512 thr), 4-sub-phase 8-phase-style
// schedule, counted vmcnt, 128KB LDS.
//
// Wave (wm=w>>2, wn=w&3) owns INTERLEAVED output rows f*32+wm*16 (f=0..7) and
// cols j*64+wn*16 (j=0..3), so:
//   A-half0 (tile rows 0-127)  read only in phases p1,p2 (f=0..3)
//   A-half1 (rows 128-255)     read only in p3,p4
//   B-half0 (cols 0-127)       read in p1,p3 ; B-half1 in p2,p4
// LDS (bytes): A[buf][half] = buf*32768 + half*16384 ; B same + 65536.
// Per K-tile t (buf=t&1), one half-tile (2 gl16) staged per phase:
//   p1: STA(t+1,h1) | dsr A-q0(8)+B-h0(4) | 16 MFMA | vmcnt(6)* | bar
//   p2: STB(t+1,h1) | dsr B-h1(4)         | 16 MFMA |            bar
//   p3: STA(t+2,h0) | dsr A-q1(8)+B-h0(4) | 16 MFMA |            bar
//   p4: STB(t+2,h0) | dsr B-h1(4)         | 16 MFMA | vmcnt(6)* | bar
// Ledger (verified): every stage target's last reader is >=1 barrier back
// (A-h1[t-1] freed @p4(t-1); B-h1[t-1] @p4(t-1); A-h0[t] @p2(t); B-h0[t]
// @p3(t)). vmcnt(6)@p1-end retires through B1(t) (needed p2); vmcnt(6)@p4-end
// retires through A1(t+1)... wait retires through A0(t+1),B0(t+1) suppliers
// (needed p1(t+1)). Tail: p1(15)->vmcnt(0); p4(14)->vmcnt(4); p4(15) none.
// Prologue: A0(0),B0(0),A1(0),B1(0),A0(1),B0(1) then vmcnt(8)+barrier.
// ---------------------------------------------------------------------------
__global__ __launch_bounds__(512)
void qkv8p(const u16* __restrict__ ws_in, const float* __restrict__ c0,
           const float* __restrict__ c1, const float* __restrict__ c2,
           u16* __restrict__ o0, u16* __restrict__ o1,
           u16* __restrict__ o2) {
  const int bid = blockIdx.x;
  const int s = (bid & 7) * 24 + (bid >> 3);  // XCD swizzle, 192 % 8 == 0
  const int z = s >> 6;
  const int rem = s & 63;
  const int m0 = (rem >> 2) << 8;
  const int n0 = (rem & 3) << 8;

  const u16* __restrict__ A = ws_in + 4194304 + z * 4194304;
  const u16* __restrict__ W = ws_in + z * 1048576;
  const float* Bi = (z == 0) ? c0 : (z == 1) ? c1 : c2;
  u16* O = (z == 0) ? o0 : (z == 1) ? o1 : o2;

  const int tid = threadIdx.x, lane = tid & 63, w = tid >> 6;
  const int wm = w >> 2, wn = w & 3;
  const int r = lane & 15, g = lane >> 4;

  __shared__ u16 SH[65536];  // 128 KB
  char* sb = (char*)SH;

  f32x4 acc[8][4] = {};
  bf16x8 afr[2][4], bfr[2][2];

  // staging addresses (linear LDS dest + inverse-swizzled source, rule 21)
  const u16* Asrc = A + (m0 + (w << 3) + (lane >> 3)) * 1024 +
                    (((lane & 7) ^ (lane >> 3)) << 3);
  const u16* Bsrc = W + (n0 + (w << 3) + (lane >> 3)) * 1024 +
                    (((lane & 7) ^ (lane >> 3)) << 3);
  u16* Adst = (u16*)SH + (w << 9);            // + buf*16384 + half*8192 (+4096)
  u16* Bdst = (u16*)SH + 32768 + (w << 9);

#define STA8(tt, h)                                                         \
  {                                                                         \
    gl16(Asrc + (h)*131072 + (tt)*64, Adst + (((tt)&1) << 14) + ((h) << 13)); \
    gl16(Asrc + (h)*131072 + 65536 + (tt)*64,                               \
         Adst + (((tt)&1) << 14) + ((h) << 13) + 4096);                     \
  }
#define STB8(tt, h)                                                         \
  {                                                                         \
    gl16(Bsrc + (h)*131072 + (tt)*64, Bdst + (((tt)&1) << 14) + ((h) << 13)); \
    gl16(Bsrc + (h)*131072 + 65536 + (tt)*64,                               \
         Bdst + (((tt)&1) << 14) + ((h) << 13) + 4096);                     \
  }

  const int colr0 = (g * 16) ^ ((r & 7) << 4);
  const int colr1 = (64 + g * 16) ^ ((r & 7) << 4);
  const int rowA = (wm * 16 + r) * 128;  // + i*32*128 within half
  const int rowB = (wn * 16 + r) * 128;  // + jj*64*128 within half

#define LDSA(qm)                                                            \
  _Pragma("unroll") for (int i = 0; i < 4; ++i) {                           \
    char* p = sb + bo + (qm)*16384 + rowA + i * 4096;                       \
    afr[0][i] = __builtin_bit_cast(bf16x8, *(const u16x8*)(p + colr0));     \
    afr[1][i] = __builtin_bit_cast(bf16x8, *(const u16x8*)(p + colr1));     \
  }
#define LDSB(qn)                                                            \
  _Pragma("unroll") for (int jj = 0; jj < 2; ++jj) {                        \
    char* p = sb + bo + 65536 + (qn)*16384 + rowB + jj * 8192;              \
    bfr[0][jj] = __builtin_bit_cast(bf16x8, *(const u16x8*)(p + colr0));    \
    bfr[1][jj] = __builtin_bit_cast(bf16x8, *(const u16x8*)(p + colr1));    \
  }
#define FMAQ(qm, qn)                                                        \
  __builtin_amdgcn_s_setprio(1);                                            \
  _Pragma("unroll") for (int i = 0; i < 4; ++i)                             \
  _Pragma("unroll") for (int jj = 0; jj < 2; ++jj) {                        \
    acc[(qm)*4 + i][(qn)*2 + jj] = MFMA16(afr[0][i], bfr[0][jj],            \
                                          acc[(qm)*4 + i][(qn)*2 + jj], 0,  \
                                          0, 0);                            \
    acc[(qm)*4 + i][(qn)*2 + jj] = MFMA16(afr[1][i], bfr[1][jj],            \
                                          acc[(qm)*4 + i][(qn)*2 + jj], 0,  \
                                          0, 0);                            \
  }                                                                         \
  __builtin_amdgcn_s_setprio(0);

  // prologue: halves in queue order A0(0),B0(0),A1(0),B1(0),A0(1),B0(1)
  STA8(0, 0);
  STB8(0, 0);
  STA8(0, 1);
  STB8(0, 1);
  STA8(1, 0);
  STB8(1, 0);
  VMCNT(8);  // A0(0),B0(0) retired
  __builtin_amdgcn_s_barrier();
  asm volatile("" ::: "memory");

  for (int t = 0; t < 16; ++t) {
    const int bo = (t & 1) << 15;
    // ---- p1: A-q0 x B-h0
    if (t < 15) STA8(t + 1, 1);
    LDSA(0);
    LDSB(0);
    FMAQ(0, 0);
    if (t < 15) { VMCNT(6); } else { VMCNT(0); }
    BARR();
    // ---- p2: A-q0 x B-h1
    if (t < 15) STB8(t + 1, 1);
    LDSB(1);
    FMAQ(0, 1);
    BARR();
    // ---- p3: A-q1 x B-h0
    if (t < 14) STA8(t + 2, 0);
    LDSA(1);
    LDSB(0);
    FMAQ(1, 0);
    BARR();
    // ---- p4: A-q1 x B-h1
    if (t < 14) STB8(t + 2, 0);
    LDSB(1);
    FMAQ(1, 1);
    if (t < 14) { VMCNT(6); } else if (t == 14) { VMCNT(4); }
    BARR();
  }

  // epilogue: C/D layout col=lane&15, row=g*4+q -> bf16 [B,H,S,64]
#pragma unroll
  for (int j = 0; j < 4; ++j) {
    const int gn = n0 + j * 64 + wn * 16 + r;
    const int hh = gn >> 6, d = gn & 63;
    const float bv = Bi[gn];
#pragma unroll
    for (int f = 0; f < 8; ++f) {
#pragma unroll
      for (int q = 0; q < 4; ++q) {
        int gm = m0 + f * 32 + wm * 16 + g * 4 + q;
        int bb = gm >> 11, sIdx = gm & 2047;
        O[((bb * 16 + hh) * 2048 + sIdx) * 64 + d] = f2bf(acc[f][j][q] + bv);
      }
    }
  }
#undef STA8
#undef STB8
#undef LDSA
#undef LDSB
#undef FMAQ
}

// ---------------------------------------------------------------------------
// 128x128 2-phase counted-vmcnt GEMM core (round-4-proven) — for out proj.
// ---------------------------------------------------------------------------
#define OSTGA(tt, c, j)                                                     \
  gl16(Ain + (m0 + (c)*64 + (w << 4) + (j)*8 + (lane >> 3)) * 1024 +        \
           (tt)*64 + (((lane & 7) ^ (lane >> 3)) << 3),                     \
       (u16*)(sb + (((tt)&1) << 15) + (c)*8192 + (w << 11) + ((j) << 10)))
#define OSTGB(tt, c, j)                                                     \
  gl16(W + (n0 + (c)*64 + (w << 4) + (j)*8 + (lane >> 3)) * 1024 +          \
           (tt)*64 + (((lane & 7) ^ (lane >> 3)) << 3),                     \
       (u16*)(sb + (((tt)&1) << 15) + 16384 + (c)*8192 + (w << 11) +        \
              ((j) << 10)))
#define OLDA()                                                              \
  _Pragma("unroll") for (int m = 0; m < 4; ++m) {                           \
    char* p = sb + bo + rowAb + m * 16 * 128;                               \
    af[0][m] = __builtin_bit_cast(bf16x8, *(const u16x8*)(p + colr0));      \
    af[1][m] = __builtin_bit_cast(bf16x8, *(const u16x8*)(p + colr1));      \
  }
#define OLDB(n)                                                             \
  {                                                                         \
    char* p = sb + bo + rowBb + (n)*16 * 128;                               \
    bf[0][n] = __builtin_bit_cast(bf16x8, *(const u16x8*)(p + colr0));      \
    bf[1][n] = __builtin_bit_cast(bf16x8, *(const u16x8*)(p + colr1));      \
  }
#define OFMA(nh)                                                            \
  __builtin_amdgcn_s_setprio(1);                                            \
  _Pragma("unroll") for (int m = 0; m < 4; ++m)                             \
  _Pragma("unroll") for (int n = 0; n < 2; ++n) {                           \
    acc[m][(nh)*2 + n] =                                                    \
        MFMA16(af[0][m], bf[0][(nh)*2 + n], acc[m][(nh)*2 + n], 0, 0, 0);   \
    acc[m][(nh)*2 + n] =                                                    \
        MFMA16(af[1][m], bf[1][(nh)*2 + n], acc[m][(nh)*2 + n], 0, 0, 0);   \
  }                                                                         \
  __builtin_amdgcn_s_setprio(0);

__device__ __forceinline__ void core128(const u16* __restrict__ Ain,
                                        const u16* __restrict__ W, int m0,
                                        int n0, char* sb,
                                        f32x4 (&acc)[4][4]) {
  const int tid = threadIdx.x, lane = tid & 63, w = tid >> 6;
  const int wm = w >> 1, wn = w & 1;
  const int r = lane & 15, g = lane >> 4;
  bf16x8 af[2][4], bf[2][4];

  const int colr0 = (g * 16) ^ ((r & 7) << 4);
  const int colr1 = (64 + g * 16) ^ ((r & 7) << 4);
  const int rowAb = (wm * 64 + r) * 128;
  const int rowBb = 16384 + (wn * 64 + r) * 128;

#pragma unroll
  for (int c = 0; c < 2; ++c) { OSTGA(0, c, 0); OSTGA(0, c, 1); }
#pragma unroll
  for (int c = 0; c < 2; ++c) { OSTGB(0, c, 0); OSTGB(0, c, 1); }
#pragma unroll
  for (int c = 0; c < 2; ++c) { OSTGA(1, c, 0); OSTGA(1, c, 1); }
  VMCNT(4);
  __builtin_amdgcn_s_barrier();
  asm volatile("" ::: "memory");

  for (int t = 0; t < 16; ++t) {
    const int bo = (t & 1) << 15;
    if (t < 15) { OSTGB(t + 1, 0, 0); OSTGB(t + 1, 0, 1); OSTGB(t + 1, 1, 0); OSTGB(t + 1, 1, 1); }
    OLDA();
    OLDB(0); OLDB(1);
    OFMA(0);
    BARR();
    if (t < 14) { OSTGA(t + 2, 0, 0); OSTGA(t + 2, 0, 1); OSTGA(t + 2, 1, 0); OSTGA(t + 2, 1, 1); }
    OLDB(2); OLDB(3);
    OFMA(1);
    if (t < 14) { VMCNT(4); } else if (t == 14) { VMCNT(0); }
    BARR();
  }
}

__global__ __launch_bounds__(256)
void out_gemm_p(const u16* __restrict__ Ain2, const u16* __restrict__ W2,
                const float* __restrict__ Bi, float* __restrict__ C) {
  const int bid = blockIdx.x;
  const int s = (bid & 7) * 32 + (bid >> 3);  // 256 % 8 == 0
  const int m0 = (s >> 3) << 7, n0 = (s & 7) << 7;

  const int tid = threadIdx.x, lane = tid & 63, w = tid >> 6;
  const int wm = w >> 1, wn = w & 1;
  const int r = lane & 15, g = lane >> 4;

  __shared__ u16 SH[32768];  // 64 KB
  f32x4 acc[4][4] = {};
  core128(Ain2, W2, m0, n0, (char*)SH, acc);

#pragma unroll
  for (int m = 0; m < 4; ++m) {
#pragma unroll
    for (int n = 0; n < 4; ++n) {
      int gn = n0 + wn * 64 + n * 16 + r;
      float bv = Bi[gn];
#pragma unroll
      for (int q = 0; q < 4; ++q) {
        int gm = m0 + wm * 64 + m * 16 + g * 4 + q;
        C[gm * 1024 + gn] = acc[m][n][q] + bv;
      }
    }
  }
}

// ---------------------------------------------------------------------------
// Sparse flash attention (unchanged). grid (32, 16, 2), 256 threads.
// ---------------------------------------------------------------------------
__global__ __launch_bounds__(256)
void attn_kernel(const u16* __restrict__ Q, const u16* __restrict__ K,
                 const u16* __restrict__ V, u16* __restrict__ O) {
  const int qt = blockIdx.x, h = blockIdx.y, b = blockIdx.z;
  const int tid = threadIdx.x, lane = tid & 63, w = tid >> 6;
  const int r = lane & 15, g = lane >> 4;
  const int q0 = qt * 64;
  const int base = (b * 16 + h) * 131072;
  const u16* Qb = Q + base;
  const u16* Kb = K + base;
  const u16* Vb = V + base;

  __shared__ u16 Ks[64 * 64];
  __shared__ u16 Vt[64 * 64];
  __shared__ u16 Pl[4608];

  bf16x8 qf[2];
  {
    const u16* qp = Qb + (q0 + w * 16 + r) * 64 + g * 8;
    qf[0] = __builtin_bit_cast(bf16x8, *(const u16x8*)qp);
    qf[1] = __builtin_bit_cast(bf16x8, *(const u16x8*)(qp + 32));
  }

  f32x4 acc[4] = {};
  float m_run[4] = {-1e30f, -1e30f, -1e30f, -1e30f};
  float l_run[4] = {};

  const int nt = (qt <= 3) ? (qt + 1) : 4;
  const int srow = tid >> 3, sc = (tid & 7) * 8;

  for (int tix = 0; tix < nt; ++tix) {
    const int t = (tix == 0) ? 0 : ((qt <= 3) ? tix : (qt - 3 + tix));
    const int j0 = t * 64;
    __syncthreads();
#pragma unroll
    for (int i = 0; i < 2; ++i) {
      int row = i * 32 + srow;
      u16x8 kv = *(const u16x8*)(Kb + (j0 + row) * 64 + sc);
      *(u16x8*)((char*)Ks + swz(row, sc * 2)) = kv;
      u16x8 vv = *(const u16x8*)(Vb + (j0 + row) * 64 + sc);
#pragma unroll
      for (int qq = 0; qq < 8; ++qq) {
        int d = sc + qq;
        *(u16*)((char*)Vt + d * 128 + ((2 * row) ^ ((d & 7) << 4))) = vv[qq];
      }
    }
    __syncthreads();

    f32x4 S[4] = {};
#pragma unroll
    for (int kk = 0; kk < 2; ++kk)
#pragma unroll
      for (int n = 0; n < 4; ++n) {
        bf16x8 kf = __builtin_bit_cast(
            bf16x8,
            *(const u16x8*)((char*)Ks + swz(n * 16 + r, kk * 64 + g * 16)));
        S[n] = MFMA16(qf[kk], kf, S[n], 0, 0, 0);
      }

    float mloc[4] = {-1e30f, -1e30f, -1e30f, -1e30f};
#pragma unroll
    for (int n = 0; n < 4; ++n) {
      int j = j0 + n * 16 + r;
#pragma unroll
      for (int q = 0; q < 4; ++q) {
        int i = q0 + w * 16 + g * 4 + q;
        bool ok = (j <= i) && (((i - j) <= 128) || (j < 16));
        float s = ok ? S[n][q] * 0.125f : -1e30f;
        S[n][q] = s;
        mloc[q] = fmaxf(mloc[q], s);
      }
    }
#pragma unroll
    for (int q = 0; q < 4; ++q)
#pragma unroll
      for (int off = 1; off < 16; off <<= 1)
        mloc[q] = fmaxf(mloc[q], __shfl_xor(mloc[q], off));

    float alpha[4], rsum[4] = {};
#pragma unroll
    for (int q = 0; q < 4; ++q) {
      float mn = fmaxf(m_run[q], mloc[q]);
      alpha[q] = __expf(m_run[q] - mn);
      m_run[q] = mn;
    }
#pragma unroll
    for (int n = 0; n < 4; ++n)
#pragma unroll
      for (int q = 0; q < 4; ++q) {
        float p = __expf(S[n][q] - m_run[q]);
        S[n][q] = p;
        rsum[q] += p;
      }
#pragma unroll
    for (int q = 0; q < 4; ++q) {
#pragma unroll
      for (int off = 1; off < 16; off <<= 1)
        rsum[q] += __shfl_xor(rsum[q], off);
      l_run[q] = l_run[q] * alpha[q] + rsum[q];
    }
#pragma unroll
    for (int n = 0; n < 4; ++n) {
      acc[n][0] *= alpha[0];
      acc[n][1] *= alpha[1];
      acc[n][2] *= alpha[2];
      acc[n][3] *= alpha[3];
    }

#pragma unroll
    for (int n = 0; n < 4; ++n)
#pragma unroll
      for (int q = 0; q < 4; ++q)
        *((u16*)((char*)Pl + w * 2304 + (g * 4 + q) * 144) + (n * 16 + r)) =
            f2bf(S[n][q]);

#pragma unroll
    for (int kk = 0; kk < 2; ++kk) {
      bf16x8 pf = __builtin_bit_cast(
          bf16x8,
          *(const u16x8*)((char*)Pl + w * 2304 + r * 144 + kk * 64 + g * 16));
#pragma unroll
      for (int n = 0; n < 4; ++n) {
        bf16x8 vf = __builtin_bit_cast(
            bf16x8,
            *(const u16x8*)((char*)Vt + swz(n * 16 + r, kk * 64 + g * 16)));
        acc[n] = MFMA16(pf, vf, acc[n], 0, 0, 0);
      }
    }
  }

#pragma unroll
  for (int n = 0; n < 4; ++n)
#pragma unroll
    for (int q = 0; q < 4; ++q) {
      int s = q0 + w * 16 + g * 4 + q;
      int d = n * 16 + r;
      O[(b * 2048 + s) * 1024 + h * 64 + d] = f2bf(acc[n][q] / l_run[q]);
    }
}

// ---------------------------------------------------------------------------
extern "C" void kernel_launch(void* const* d_in, const int* in_sizes, int n_in,
                              void* d_out, int out_size, void* d_ws,
                              size_t ws_size, hipStream_t stream) {
  const float* b_q = (const float*)d_in[4];
  const float* b_k = (const float*)d_in[6];
  const float* b_v = (const float*)d_in[8];
  const float* b_o = (const float*)d_in[10];

  u16* ws = (u16*)d_ws;
  u16* Qw = ws + 16777216;
  u16* Kw = ws + 20971520;
  u16* Vw = ws + 25165824;
  u16* Aw = ws + 4194304;  // aliases Xq (dead after qkv projection)

  cast_all<<<dim3(8192), dim3(256), 0, stream>>>(
      (const float*)d_in[0], (const float*)d_in[1], (const float*)d_in[2],
      (const float*)d_in[3], (const float*)d_in[5], (const float*)d_in[7],
      (const float*)d_in[9], ws);
  qkv8p<<<dim3(192), dim3(512), 0, stream>>>(ws, b_q, b_k, b_v, Qw, Kw, Vw);
  attn_kernel<<<dim3(32, 16, 2), dim3(256), 0, stream>>>(Qw, Kw, Vw, Aw);
  out_gemm_p<<<dim3(256), dim3(256), 0, stream>>>(Aw, ws + 3145728, b_o,
                                                  (float*)d_out);
}